// Round 7
// baseline (246.418 us; speedup 1.0000x reference)
//
#include <hip/hip_runtime.h>
#include <hip/hip_bf16.h>
#include <stdint.h>

#define NNODES 10000
#define NEDGES 320000
#define DIM    256
#define KTOT   512
#define LN_EPS 1e-5f

typedef __attribute__((ext_vector_type(4))) float f32x4;
typedef __attribute__((ext_vector_type(8))) short bf16x8;

__device__ __forceinline__ ushort f2bf(float f) {
    union { float f; uint32_t u; } v; v.f = f;
    uint32_t r = v.u + 0x7fffu + ((v.u >> 16) & 1u);   // RNE
    return (ushort)(r >> 16);
}
__device__ __forceinline__ float bf2f(ushort u) {
    union { float f; uint32_t u; } v; v.u = ((uint32_t)u) << 16;
    return v.f;
}

// cast n4*4 floats -> bf16 (vectorized float4 -> ushort4)
__global__ void prep_cast(const float* __restrict__ src, ushort* __restrict__ dst, int n4) {
    int i = blockIdx.x * blockDim.x + threadIdx.x;
    if (i >= n4) return;
    float4 v = reinterpret_cast<const float4*>(src)[i];
    ushort4 o;
    o.x = f2bf(v.x); o.y = f2bf(v.y); o.z = f2bf(v.z); o.w = f2bf(v.w);
    reinterpret_cast<ushort4*>(dst)[i] = o;
}

// Edge W: Wa[h][kk][wc][nt][kg][ml][j] -> lane-linear 1KB frag loads
//   idx = h*65536 + kk*4096 + wc*2048 + nt*512 + kg*128 + ml*8 + j
//   = W_msg[kk*32+kg*8+j][h*128 + wc*64 + nt*16 + ml]
// Node W: Wua[kk][nt16][kg][ml][j]
//   idx = kk*8192 + nt16*512 + kg*128 + ml*8 + j = W_upd[kk*32+kg*8+j][nt16*16 + ml]
__global__ void prep_wt(const float* __restrict__ Wm, const float* __restrict__ Wu,
                        ushort* __restrict__ Wa, ushort* __restrict__ Wua) {
    int tid = blockIdx.x * blockDim.x + threadIdx.x;   // 262144 threads
    if (tid < 131072) {
        int h   = tid >> 16;
        int rem = tid & 65535;
        int kk  = rem >> 12;
        int wc  = (rem >> 11) & 1;
        int nt  = (rem >> 9) & 3;
        int kg  = (rem >> 7) & 3;
        int ml  = (rem >> 3) & 15;
        int j   = rem & 7;
        int k = kk * 32 + kg * 8 + j;
        int n = h * 128 + wc * 64 + nt * 16 + ml;
        Wa[tid] = f2bf(Wm[k * DIM + n]);
    } else {
        int rem = tid - 131072;
        int kk  = rem >> 13;
        int nt  = (rem >> 9) & 15;
        int kg  = (rem >> 7) & 3;
        int ml  = (rem >> 3) & 15;
        int j   = rem & 7;
        int k = kk * 32 + kg * 8 + j;
        int n = nt * 16 + ml;
        Wua[rem] = f2bf(Wu[k * DIM + n]);
    }
}

// ---- counting sort of edges by destination ----
__global__ void hist_k(const int* __restrict__ eidx, int* __restrict__ cnt) {
    int e = blockIdx.x * blockDim.x + threadIdx.x;
    if (e < NEDGES) atomicAdd(&cnt[eidx[NEDGES + e]], 1);
}

__global__ void scan_k(const int* __restrict__ cnt, int* __restrict__ cursor) {
    __shared__ int ts[256];
    int t = threadIdx.x;
    int base = t * 40;                       // 256*40 = 10240 >= NNODES
    int s = 0;
    for (int i = 0; i < 40; ++i) { int idx = base + i; if (idx < NNODES) s += cnt[idx]; }
    ts[t] = s;
    __syncthreads();
    int run = s;
    for (int off = 1; off < 256; off <<= 1) {   // Hillis-Steele inclusive scan
        int v = (t >= off) ? ts[t - off] : 0;
        __syncthreads();
        run += v;
        ts[t] = run;
        __syncthreads();
    }
    int o = run - s;                            // exclusive prefix
    for (int i = 0; i < 40; ++i) {
        int idx = base + i;
        if (idx < NNODES) { cursor[idx] = o; o += cnt[idx]; }
    }
}

__global__ void scatter_k(const int* __restrict__ eidx, int* __restrict__ cursor,
                          int* __restrict__ srow, int* __restrict__ sdst) {
    int e = blockIdx.x * blockDim.x + threadIdx.x;
    if (e >= NEDGES) return;
    int d = eidx[NEDGES + e];
    int r = eidx[e];
    int p = atomicAdd(&cursor[d], 1);
    srow[p] = r;
    sdst[p] = d;
}

// ---- edge message GEMM: barrier-free, B direct from global (L1/L2-resident) ----
// Grid: 2500 edge-tiles(128) x 2 col-halves(128). Block 256 thr = 4 waves
// (we = edge group of 64, wc = col group of 64). Wave: 64 edges x 64 cols.
// K-loop: NO LDS, NO barriers. A rotates through THREE reg buffers (depth-2
// prefetch; consume a[kk%3], prefetch a[(kk+2)%3] -- fixes R6's overwrite bug),
// B double-buffered depth-1.
#define EPREF(BUF, KN) do { \
    _Pragma("unroll") for (int et = 0; et < 4; ++et) { \
        uint o = ((KN) < 8 ? osrc[et] + (KN) * 32 : odst[et] + ((KN) - 8) * 32) + kg * 8; \
        BUF[et] = *reinterpret_cast<const bf16x8*>(xb + o); } } while (0)

#define BPREF(BUF, KN) do { \
    _Pragma("unroll") for (int nt = 0; nt < 4; ++nt) \
        BUF[nt] = *reinterpret_cast<const bf16x8*>(WaB + (KN) * 4096 + nt * 512 + lane * 8); } while (0)

#define ESTEP(AB, BB) do { \
    _Pragma("unroll") for (int nt = 0; nt < 4; ++nt) \
        _Pragma("unroll") for (int et = 0; et < 4; ++et) \
            acc[et][nt] = __builtin_amdgcn_mfma_f32_16x16x32_bf16(AB[et], BB[nt], acc[et][nt], 0, 0, 0); } while (0)

__global__ __launch_bounds__(256, 3)
void edge_gemm(const ushort* __restrict__ xb, const int* __restrict__ srow,
               const int* __restrict__ sdst, const ushort* __restrict__ Wa,
               const float* __restrict__ bmsg, float* __restrict__ agg) {
    __shared__ ushort Ds[16896];     // epilogue staging: 128 cols x 132 stride
    __shared__ int dstS[128];

    const int tid  = threadIdx.x;
    const int wave = tid >> 6, lane = tid & 63;
    const int ml = lane & 15, kg = lane >> 4;
    const int we = wave >> 1, wc = wave & 1;
    const int h     = blockIdx.x & 1;
    const int tile  = blockIdx.x >> 1;
    const int ebase = tile * 128;

    uint osrc[4], odst[4];
#pragma unroll
    for (int et = 0; et < 4; ++et) {
        int e = ebase + we * 64 + et * 16 + ml;
        osrc[et] = (uint)srow[e] * DIM;
        odst[et] = (uint)sdst[e] * DIM;
    }
    if (tid < 128) dstS[tid] = sdst[ebase + tid];

    const ushort* WaB = Wa + ((size_t)h << 16) + wc * 2048;

    bf16x8 a0[4], a1[4], a2[4], b0[4], b1[4];
    EPREF(a0, 0);
    EPREF(a1, 1);
    BPREF(b0, 0);

    f32x4 acc[4][4];
#pragma unroll
    for (int et = 0; et < 4; ++et)
#pragma unroll
        for (int nt = 0; nt < 4; ++nt) acc[et][nt] = (f32x4){0.f, 0.f, 0.f, 0.f};

#pragma unroll
    for (int kk = 0; kk < 16; ++kk) {
        // B: prefetch next into the other buffer, consume b[kk&1]
        if ((kk & 1) == 0) { if (kk < 15) BPREF(b1, kk + 1); }
        else               { if (kk < 15) BPREF(b0, kk + 1); }
        // A: prefetch kk+2 into a[(kk+2)%3], consume a[kk%3]  (3-buffer rotation)
        if (kk % 3 == 0) {
            if (kk < 14) EPREF(a2, kk + 2);
            if ((kk & 1) == 0) ESTEP(a0, b0); else ESTEP(a0, b1);
        } else if (kk % 3 == 1) {
            if (kk < 14) EPREF(a0, kk + 2);
            if ((kk & 1) == 0) ESTEP(a1, b0); else ESTEP(a1, b1);
        } else {
            if (kk < 14) EPREF(a1, kk + 2);
            if ((kk & 1) == 0) ESTEP(a2, b0); else ESTEP(a2, b1);
        }
    }

    // ---- epilogue: bias+relu -> bf16 Ds[col][edge] -> segmented reduce ----
    const int hbase = h << 7;
#pragma unroll
    for (int nt = 0; nt < 4; ++nt) {
        const int c = wc * 64 + nt * 16 + ml;
        const float bb = bmsg[hbase + c];
#pragma unroll
        for (int et = 0; et < 4; ++et) {
            ushort4 pk;
#pragma unroll
            for (int i = 0; i < 4; ++i) {
                float v = acc[et][nt][i] + bb;
                v = v > 0.f ? v : 0.f;
                ((ushort*)&pk)[i] = f2bf(v);
            }
            *reinterpret_cast<ushort4*>(&Ds[c * 132 + we * 64 + et * 16 + kg * 4]) = pk;
        }
    }
    __syncthreads();

    // segmented reduce: thread (c = tid&127, q = tid>>7) scans 64 sorted edges
    const int c = tid & 127, q = tid >> 7;
    const int rbase = q * 64;
    float s = 0.f;
    int dprev = dstS[rbase];
    for (int i4 = 0; i4 < 16; ++i4) {
        int4 dd = *reinterpret_cast<const int4*>(&dstS[rbase + i4 * 4]);
        ushort4 vv = *reinterpret_cast<const ushort4*>(&Ds[c * 132 + rbase + i4 * 4]);
        if (dd.x == dprev && dd.y == dprev && dd.z == dprev && dd.w == dprev) {
            s += bf2f(vv.x) + bf2f(vv.y) + bf2f(vv.z) + bf2f(vv.w);
        } else {
            int dj[4] = {dd.x, dd.y, dd.z, dd.w};
#pragma unroll
            for (int j = 0; j < 4; ++j) {
                if (dj[j] != dprev) {
                    if (s != 0.f) atomicAdd(&agg[(size_t)dprev * DIM + hbase + c], s);
                    s = 0.f; dprev = dj[j];
                }
                s += bf2f(((const ushort*)&vv)[j]);
            }
        }
    }
    if (s != 0.f) atomicAdd(&agg[(size_t)dprev * DIM + hbase + c], s);
}

#undef EPREF
#undef BPREF
#undef ESTEP

// ---- node update GEMM + bias + relu + LayerNorm ----
// 625 blocks x 256 thr (4 waves). Block = 16 nodes x 256 cols; wave wq handles
// cols [wq*64, wq*64+64) over full K=512 (acc[4] = 16 regs). LN partials
// combined across the 4 waves via a tiny LDS exchange. B direct from global.
__global__ __launch_bounds__(256)
void node_gemm_ln(const ushort* __restrict__ xb, const float* __restrict__ agg,
                  const ushort* __restrict__ Wua, const float* __restrict__ bupd,
                  const float* __restrict__ gamma, const float* __restrict__ beta,
                  float* __restrict__ out) {
    __shared__ float pS[16][4][2];     // [node][wave][sum,ssq]

    const int wq   = threadIdx.x >> 6;
    const int lane = threadIdx.x & 63;
    const int ml = lane & 15, kg = lane >> 4;
    const int nb = blockIdx.x * 16;
    const uint arow = (uint)(nb + ml) * DIM;          // 625*16 = 10000 exactly

    f32x4 acc[4];
#pragma unroll
    for (int nt = 0; nt < 4; ++nt) acc[nt] = (f32x4){0.f, 0.f, 0.f, 0.f};

#pragma unroll
    for (int kk = 0; kk < 8; ++kk) {                  // k in [0,256): A = xb
        bf16x8 a = *reinterpret_cast<const bf16x8*>(xb + arow + kk * 32 + kg * 8);
#pragma unroll
        for (int nt = 0; nt < 4; ++nt) {
            bf16x8 b = *reinterpret_cast<const bf16x8*>(Wua + kk * 8192 + (wq * 4 + nt) * 512 + lane * 8);
            acc[nt] = __builtin_amdgcn_mfma_f32_16x16x32_bf16(a, b, acc[nt], 0, 0, 0);
        }
    }
#pragma unroll
    for (int kk = 0; kk < 8; ++kk) {                  // k in [256,512): A = agg (fp32)
        float4 f0 = *reinterpret_cast<const float4*>(agg + arow + kk * 32 + kg * 8);
        float4 f1 = *reinterpret_cast<const float4*>(agg + arow + kk * 32 + kg * 8 + 4);
        union { bf16x8 v; __hip_bfloat162 h2[4]; } u;
        u.h2[0] = __float22bfloat162_rn(make_float2(f0.x, f0.y));
        u.h2[1] = __float22bfloat162_rn(make_float2(f0.z, f0.w));
        u.h2[2] = __float22bfloat162_rn(make_float2(f1.x, f1.y));
        u.h2[3] = __float22bfloat162_rn(make_float2(f1.z, f1.w));
#pragma unroll
        for (int nt = 0; nt < 4; ++nt) {
            bf16x8 b = *reinterpret_cast<const bf16x8*>(Wua + 65536 + kk * 8192 + (wq * 4 + nt) * 512 + lane * 8);
            acc[nt] = __builtin_amdgcn_mfma_f32_16x16x32_bf16(u.v, b, acc[nt], 0, 0, 0);
        }
    }

    // bias + relu + per-wave partial sums (this wave's 64 cols)
    float sum[4] = {0.f, 0.f, 0.f, 0.f}, ssq[4] = {0.f, 0.f, 0.f, 0.f};
#pragma unroll
    for (int nt = 0; nt < 4; ++nt) {
        const float bb = bupd[wq * 64 + nt * 16 + ml];
#pragma unroll
        for (int i = 0; i < 4; ++i) {
            float v = acc[nt][i] + bb;
            v = v > 0.f ? v : 0.f;
            acc[nt][i] = v;
            sum[i] += v;
            ssq[i] += v * v;
        }
    }
#pragma unroll
    for (int m = 1; m < 16; m <<= 1) {
#pragma unroll
        for (int i = 0; i < 4; ++i) {
            sum[i] += __shfl_xor(sum[i], m);
            ssq[i] += __shfl_xor(ssq[i], m);
        }
    }
    if (ml == 0) {
#pragma unroll
        for (int i = 0; i < 4; ++i) {
            pS[kg * 4 + i][wq][0] = sum[i];
            pS[kg * 4 + i][wq][1] = ssq[i];
        }
    }
    __syncthreads();

    float mu[4], rs[4];
#pragma unroll
    for (int i = 0; i < 4; ++i) {
        int r = kg * 4 + i;
        float S = pS[r][0][0] + pS[r][1][0] + pS[r][2][0] + pS[r][3][0];
        float Q = pS[r][0][1] + pS[r][1][1] + pS[r][2][1] + pS[r][3][1];
        float m = S * (1.f / 256.f);
        float var = Q * (1.f / 256.f) - m * m;
        mu[i] = m;
        rs[i] = rsqrtf(var + LN_EPS);
    }
#pragma unroll
    for (int nt = 0; nt < 4; ++nt) {
        const int cc = wq * 64 + nt * 16 + ml;
        const float g = gamma[cc], be = beta[cc];
#pragma unroll
        for (int i = 0; i < 4; ++i) {
            const int node = nb + kg * 4 + i;
            out[(size_t)node * DIM + cc] = (acc[nt][i] - mu[i]) * rs[i] * g + be;
        }
    }
}

extern "C" void kernel_launch(void* const* d_in, const int* in_sizes, int n_in,
                              void* d_out, int out_size, void* d_ws, size_t ws_size,
                              hipStream_t stream) {
    const float* x    = (const float*)d_in[0];
    const int*   eidx = (const int*)  d_in[1];
    const float* Wm   = (const float*)d_in[2];
    const float* bm   = (const float*)d_in[3];
    const float* Wu   = (const float*)d_in[4];
    const float* bu   = (const float*)d_in[5];
    const float* gam  = (const float*)d_in[6];
    const float* bet  = (const float*)d_in[7];
    float* out = (float*)d_out;

    char* ws = (char*)d_ws;
    float*  agg    = (float*) (ws);                    // 10,240,000 B
    ushort* xb     = (ushort*)(ws + 10240000);         //  5,120,000 B
    ushort* Wa     = (ushort*)(ws + 15360000);         //    262,144 B (edge W, arranged)
    ushort* Wua    = (ushort*)(ws + 15622144);         //    262,144 B (node W, arranged)
    int*    cnt    = (int*)   (ws + 15884288);         //     40,960 B
    int*    cursor = (int*)   (ws + 15925248);         //     40,960 B
    int*    srow   = (int*)   (ws + 15966208);         //  1,280,000 B
    int*    sdst   = (int*)   (ws + 17246208);         //  1,280,000 B

    hipMemsetAsync(agg, 0, (size_t)NNODES * DIM * sizeof(float), stream);
    hipMemsetAsync(cnt, 0, (size_t)NNODES * sizeof(int), stream);
    prep_cast<<<(NNODES * DIM / 4 + 255) / 256, 256, 0, stream>>>(x, xb, NNODES * DIM / 4);
    prep_wt<<<(2 * KTOT * DIM) / 256, 256, 0, stream>>>(Wm, Wu, Wa, Wua);
    hist_k<<<(NEDGES + 255) / 256, 256, 0, stream>>>(eidx, cnt);
    scan_k<<<1, 256, 0, stream>>>(cnt, cursor);
    scatter_k<<<(NEDGES + 255) / 256, 256, 0, stream>>>(eidx, cursor, srow, sdst);
    edge_gemm<<<2 * (NEDGES / 128), 256, 0, stream>>>(xb, srow, sdst, Wa, bm, agg);
    node_gemm_ln<<<NNODES / 16, 256, 0, stream>>>(xb, agg, Wua, bu, gam, bet, out);
}

// Round 8
// 149.741 us; speedup vs baseline: 1.6456x; 1.6456x over previous
//
#include <hip/hip_runtime.h>
#include <hip/hip_bf16.h>
#include <stdint.h>

#define NNODES 10000
#define NEDGES 320000
#define DIM    256
#define KTOT   512
#define LN_EPS 1e-5f

typedef __attribute__((ext_vector_type(4))) float f32x4;
typedef __attribute__((ext_vector_type(8))) short bf16x8;

__device__ __forceinline__ ushort f2bf(float f) {
    union { float f; uint32_t u; } v; v.f = f;
    uint32_t r = v.u + 0x7fffu + ((v.u >> 16) & 1u);   // RNE
    return (ushort)(r >> 16);
}
__device__ __forceinline__ float bf2f(ushort u) {
    union { float f; uint32_t u; } v; v.u = ((uint32_t)u) << 16;
    return v.f;
}

// cast n4*4 floats -> bf16 (vectorized float4 -> ushort4)
__global__ void prep_cast(const float* __restrict__ src, ushort* __restrict__ dst, int n4) {
    int i = blockIdx.x * blockDim.x + threadIdx.x;
    if (i >= n4) return;
    float4 v = reinterpret_cast<const float4*>(src)[i];
    ushort4 o;
    o.x = f2bf(v.x); o.y = f2bf(v.y); o.z = f2bf(v.z); o.w = f2bf(v.w);
    reinterpret_cast<ushort4*>(dst)[i] = o;
}

// Wcat: fragment-arranged bf16 for the U|V GEMM (K=256, N=512).
//   idx = kk*16384 + g*512 + kg*128 + ml*8 + j ; k = kk*32+kg*8+j ; n = g*16+ml
//   n<256 -> W_msg[k][n] (U / src half) ; n>=256 -> W_msg[k+256][n-256] (V / dst half)
// Wua: node-update W (K=512, N=256), same as before:
//   idx = kk*8192 + nt*512 + kg*128 + ml*8 + j = W_upd[kk*32+kg*8+j][nt*16+ml]
__global__ void prep_wt(const float* __restrict__ Wm, const float* __restrict__ Wu,
                        ushort* __restrict__ Wcat, ushort* __restrict__ Wua) {
    int tid = blockIdx.x * blockDim.x + threadIdx.x;   // 262144 threads
    if (tid < 131072) {
        int kk  = tid >> 14;
        int rem = tid & 16383;
        int g   = rem >> 9;
        int kg  = (rem >> 7) & 3;
        int ml  = (rem >> 3) & 15;
        int j   = rem & 7;
        int k = kk * 32 + kg * 8 + j;
        int n = g * 16 + ml;
        float v = (n < 256) ? Wm[k * DIM + n] : Wm[(k + 256) * DIM + (n - 256)];
        Wcat[tid] = f2bf(v);
    } else {
        int rem = tid - 131072;
        int kk  = rem >> 13;
        int nt  = (rem >> 9) & 15;
        int kg  = (rem >> 7) & 3;
        int ml  = (rem >> 3) & 15;
        int j   = rem & 7;
        int k = kk * 32 + kg * 8 + j;
        int n = nt * 16 + ml;
        Wua[rem] = f2bf(Wu[k * DIM + n]);
    }
}

// ---- counting sort of edges by destination ----
__global__ void hist_k(const int* __restrict__ eidx, int* __restrict__ cnt) {
    int e = blockIdx.x * blockDim.x + threadIdx.x;
    if (e < NEDGES) atomicAdd(&cnt[eidx[NEDGES + e]], 1);
}

__global__ void scan_k(const int* __restrict__ cnt, int* __restrict__ cursor) {
    __shared__ int ts[256];
    int t = threadIdx.x;
    int base = t * 40;                       // 256*40 = 10240 >= NNODES
    int s = 0;
    for (int i = 0; i < 40; ++i) { int idx = base + i; if (idx < NNODES) s += cnt[idx]; }
    ts[t] = s;
    __syncthreads();
    int run = s;
    for (int off = 1; off < 256; off <<= 1) {   // Hillis-Steele inclusive scan
        int v = (t >= off) ? ts[t - off] : 0;
        __syncthreads();
        run += v;
        ts[t] = run;
        __syncthreads();
    }
    int o = run - s;                            // exclusive prefix
    for (int i = 0; i < 40; ++i) {
        int idx = base + i;
        if (idx < NNODES) { cursor[idx] = o; o += cnt[idx]; }
    }
}

__global__ void scatter_k(const int* __restrict__ eidx, int* __restrict__ cursor,
                          int* __restrict__ srow, int* __restrict__ sdst) {
    int e = blockIdx.x * blockDim.x + threadIdx.x;
    if (e >= NEDGES) return;
    int d = eidx[NEDGES + e];
    int r = eidx[e];
    int p = atomicAdd(&cursor[d], 1);
    srow[p] = r;
    sdst[p] = d;
}

// ---- U|V GEMM: U = x @ W_msg[:256]  (bf16 out), V = x @ W_msg[256:] + b (fp32 out)
// 625 blocks x 256 thr (4 waves). Block = 16 nodes x 512 cols; wave wq owns
// cols [wq*128, +128) of the concatenated [U|V] output. K = 256 (x only).
__global__ __launch_bounds__(256)
void uv_gemm(const ushort* __restrict__ xb, const ushort* __restrict__ Wcat,
             const float* __restrict__ bmsg, ushort* __restrict__ Ub,
             float* __restrict__ Vf) {
    const int wq   = threadIdx.x >> 6;
    const int lane = threadIdx.x & 63;
    const int ml = lane & 15, kg = lane >> 4;
    const int nb = blockIdx.x * 16;
    const uint arow = (uint)(nb + ml) * DIM;

    f32x4 acc[8];
#pragma unroll
    for (int nt = 0; nt < 8; ++nt) acc[nt] = (f32x4){0.f, 0.f, 0.f, 0.f};

#pragma unroll
    for (int kk = 0; kk < 8; ++kk) {
        bf16x8 a = *reinterpret_cast<const bf16x8*>(xb + arow + kk * 32 + kg * 8);
#pragma unroll
        for (int nt = 0; nt < 8; ++nt) {
            bf16x8 b = *reinterpret_cast<const bf16x8*>(Wcat + kk * 16384 + (wq * 8 + nt) * 512 + lane * 8);
            acc[nt] = __builtin_amdgcn_mfma_f32_16x16x32_bf16(a, b, acc[nt], 0, 0, 0);
        }
    }

    if (wq < 2) {                                   // U half: bf16
#pragma unroll
        for (int nt = 0; nt < 8; ++nt) {
            const int col = wq * 128 + nt * 16 + ml;
#pragma unroll
            for (int i = 0; i < 4; ++i)
                Ub[(size_t)(nb + kg * 4 + i) * 256 + col] = f2bf(acc[nt][i]);
        }
    } else {                                        // V half: fp32, bias folded in
#pragma unroll
        for (int nt = 0; nt < 8; ++nt) {
            const int col = (wq - 2) * 128 + nt * 16 + ml;
            const float bb = bmsg[col];
#pragma unroll
            for (int i = 0; i < 4; ++i)
                Vf[(size_t)(nb + kg * 4 + i) * 256 + col] = acc[nt][i] + bb;
        }
    }
}

// ---- edge combine: agg[d] = sum over edges (dst=d) of relu(U[src] + V[d]) ----
// dst-sorted edges. 1250 blocks x 512 thr; block = 256 edges. Thread (cp,q):
// cp = column pair (2 cols via one u32 load), q = edge-quarter (64 edges).
// V[d]+b is constant per segment -> loaded once per dst change (L1-cached).
__global__ __launch_bounds__(512)
void edge_combine(const ushort* __restrict__ Ub, const float* __restrict__ Vf,
                  const int* __restrict__ srow, const int* __restrict__ sdst,
                  float* __restrict__ agg) {
    __shared__ int sS[256], dS[256];

    const int tid = threadIdx.x;
    const int ebase = blockIdx.x * 256;
    if (tid < 256) sS[tid] = srow[ebase + tid];
    else           dS[tid - 256] = sdst[ebase + tid - 256];
    __syncthreads();

    const int cp = tid & 127, q = tid >> 7;
    const int c0 = cp * 2;
    const int rb = q * 64;

    float s0 = 0.f, s1 = 0.f;
    int dprev = dS[rb];
    float2 Kc = *reinterpret_cast<const float2*>(&Vf[(size_t)dprev * 256 + c0]);

#pragma unroll 1
    for (int i8 = 0; i8 < 8; ++i8) {
        uint u[8];
#pragma unroll
        for (int j = 0; j < 8; ++j)
            u[j] = *reinterpret_cast<const uint*>(&Ub[(size_t)sS[rb + i8 * 8 + j] * 256 + c0]);
#pragma unroll
        for (int j = 0; j < 8; ++j) {
            int d = dS[rb + i8 * 8 + j];
            if (d != dprev) {
                if (s0 != 0.f) atomicAdd(&agg[(size_t)dprev * DIM + c0], s0);
                if (s1 != 0.f) atomicAdd(&agg[(size_t)dprev * DIM + c0 + 1], s1);
                s0 = s1 = 0.f; dprev = d;
                Kc = *reinterpret_cast<const float2*>(&Vf[(size_t)d * 256 + c0]);
            }
            float ulo = bf2f((ushort)(u[j] & 0xffffu));
            float uhi = bf2f((ushort)(u[j] >> 16));
            float v0 = ulo + Kc.x; s0 += (v0 > 0.f) ? v0 : 0.f;
            float v1 = uhi + Kc.y; s1 += (v1 > 0.f) ? v1 : 0.f;
        }
    }
    if (s0 != 0.f) atomicAdd(&agg[(size_t)dprev * DIM + c0], s0);
    if (s1 != 0.f) atomicAdd(&agg[(size_t)dprev * DIM + c0 + 1], s1);
}

// ---- node update GEMM + bias + relu + LayerNorm ----
// 625 blocks x 256 thr (4 waves). Block = 16 nodes x 256 cols; wave wq handles
// cols [wq*64, +64) over full K=512. LN partials combined via tiny LDS exchange.
__global__ __launch_bounds__(256)
void node_gemm_ln(const ushort* __restrict__ xb, const float* __restrict__ agg,
                  const ushort* __restrict__ Wua, const float* __restrict__ bupd,
                  const float* __restrict__ gamma, const float* __restrict__ beta,
                  float* __restrict__ out) {
    __shared__ float pS[16][4][2];     // [node][wave][sum,ssq]

    const int wq   = threadIdx.x >> 6;
    const int lane = threadIdx.x & 63;
    const int ml = lane & 15, kg = lane >> 4;
    const int nb = blockIdx.x * 16;
    const uint arow = (uint)(nb + ml) * DIM;          // 625*16 = 10000 exactly

    f32x4 acc[4];
#pragma unroll
    for (int nt = 0; nt < 4; ++nt) acc[nt] = (f32x4){0.f, 0.f, 0.f, 0.f};

#pragma unroll
    for (int kk = 0; kk < 8; ++kk) {                  // k in [0,256): A = xb
        bf16x8 a = *reinterpret_cast<const bf16x8*>(xb + arow + kk * 32 + kg * 8);
#pragma unroll
        for (int nt = 0; nt < 4; ++nt) {
            bf16x8 b = *reinterpret_cast<const bf16x8*>(Wua + kk * 8192 + (wq * 4 + nt) * 512 + lane * 8);
            acc[nt] = __builtin_amdgcn_mfma_f32_16x16x32_bf16(a, b, acc[nt], 0, 0, 0);
        }
    }
#pragma unroll
    for (int kk = 0; kk < 8; ++kk) {                  // k in [256,512): A = agg (fp32)
        float4 f0 = *reinterpret_cast<const float4*>(agg + arow + kk * 32 + kg * 8);
        float4 f1 = *reinterpret_cast<const float4*>(agg + arow + kk * 32 + kg * 8 + 4);
        union { bf16x8 v; __hip_bfloat162 h2[4]; } u;
        u.h2[0] = __float22bfloat162_rn(make_float2(f0.x, f0.y));
        u.h2[1] = __float22bfloat162_rn(make_float2(f0.z, f0.w));
        u.h2[2] = __float22bfloat162_rn(make_float2(f1.x, f1.y));
        u.h2[3] = __float22bfloat162_rn(make_float2(f1.z, f1.w));
#pragma unroll
        for (int nt = 0; nt < 4; ++nt) {
            bf16x8 b = *reinterpret_cast<const bf16x8*>(Wua + 65536 + kk * 8192 + (wq * 4 + nt) * 512 + lane * 8);
            acc[nt] = __builtin_amdgcn_mfma_f32_16x16x32_bf16(u.v, b, acc[nt], 0, 0, 0);
        }
    }

    // bias + relu + per-wave partial sums (this wave's 64 cols)
    float sum[4] = {0.f, 0.f, 0.f, 0.f}, ssq[4] = {0.f, 0.f, 0.f, 0.f};
#pragma unroll
    for (int nt = 0; nt < 4; ++nt) {
        const float bb = bupd[wq * 64 + nt * 16 + ml];
#pragma unroll
        for (int i = 0; i < 4; ++i) {
            float v = acc[nt][i] + bb;
            v = v > 0.f ? v : 0.f;
            acc[nt][i] = v;
            sum[i] += v;
            ssq[i] += v * v;
        }
    }
#pragma unroll
    for (int m = 1; m < 16; m <<= 1) {
#pragma unroll
        for (int i = 0; i < 4; ++i) {
            sum[i] += __shfl_xor(sum[i], m);
            ssq[i] += __shfl_xor(ssq[i], m);
        }
    }
    if (ml == 0) {
#pragma unroll
        for (int i = 0; i < 4; ++i) {
            pS[kg * 4 + i][wq][0] = sum[i];
            pS[kg * 4 + i][wq][1] = ssq[i];
        }
    }
    __syncthreads();

    float mu[4], rs[4];
#pragma unroll
    for (int i = 0; i < 4; ++i) {
        int r = kg * 4 + i;
        float S = pS[r][0][0] + pS[r][1][0] + pS[r][2][0] + pS[r][3][0];
        float Q = pS[r][0][1] + pS[r][1][1] + pS[r][2][1] + pS[r][3][1];
        float m = S * (1.f / 256.f);
        float var = Q * (1.f / 256.f) - m * m;
        mu[i] = m;
        rs[i] = rsqrtf(var + LN_EPS);
    }
#pragma unroll
    for (int nt = 0; nt < 4; ++nt) {
        const int cc = wq * 64 + nt * 16 + ml;
        const float g = gamma[cc], be = beta[cc];
#pragma unroll
        for (int i = 0; i < 4; ++i) {
            const int node = nb + kg * 4 + i;
            out[(size_t)node * DIM + cc] = (acc[nt][i] - mu[i]) * rs[i] * g + be;
        }
    }
}

extern "C" void kernel_launch(void* const* d_in, const int* in_sizes, int n_in,
                              void* d_out, int out_size, void* d_ws, size_t ws_size,
                              hipStream_t stream) {
    const float* x    = (const float*)d_in[0];
    const int*   eidx = (const int*)  d_in[1];
    const float* Wm   = (const float*)d_in[2];
    const float* bm   = (const float*)d_in[3];
    const float* Wu   = (const float*)d_in[4];
    const float* bu   = (const float*)d_in[5];
    const float* gam  = (const float*)d_in[6];
    const float* bet  = (const float*)d_in[7];
    float* out = (float*)d_out;

    char* ws = (char*)d_ws;
    float*  agg    = (float*) (ws);                    // 10,240,000 B
    ushort* xb     = (ushort*)(ws + 10240000);         //  5,120,000 B
    ushort* Ub     = (ushort*)(ws + 15360000);         //  5,120,000 B
    float*  Vf     = (float*) (ws + 20480000);         // 10,240,000 B
    ushort* Wcat   = (ushort*)(ws + 30720000);         //    262,144 B
    ushort* Wua    = (ushort*)(ws + 30982144);         //    262,144 B
    int*    cnt    = (int*)   (ws + 31244288);         //     40,960 B
    int*    cursor = (int*)   (ws + 31285248);         //     40,960 B
    int*    srow   = (int*)   (ws + 31326208);         //  1,280,000 B
    int*    sdst   = (int*)   (ws + 32606208);         //  1,280,000 B (end ~33.9 MB)

    hipMemsetAsync(agg, 0, (size_t)NNODES * DIM * sizeof(float), stream);
    hipMemsetAsync(cnt, 0, (size_t)NNODES * sizeof(int), stream);
    prep_cast<<<(NNODES * DIM / 4 + 255) / 256, 256, 0, stream>>>(x, xb, NNODES * DIM / 4);
    prep_wt<<<(2 * KTOT * DIM) / 256, 256, 0, stream>>>(Wm, Wu, Wcat, Wua);
    hist_k<<<(NEDGES + 255) / 256, 256, 0, stream>>>(eidx, cnt);
    scan_k<<<1, 256, 0, stream>>>(cnt, cursor);
    scatter_k<<<(NEDGES + 255) / 256, 256, 0, stream>>>(eidx, cursor, srow, sdst);
    uv_gemm<<<NNODES / 16, 256, 0, stream>>>(xb, Wcat, bm, Ub, Vf);
    edge_combine<<<NEDGES / 256, 512, 0, stream>>>(Ub, Vf, srow, sdst, agg);
    node_gemm_ln<<<NNODES / 16, 256, 0, stream>>>(xb, agg, Wua, bu, gam, bet, out);
}

// Round 9
// 138.108 us; speedup vs baseline: 1.7842x; 1.0842x over previous
//
#include <hip/hip_runtime.h>
#include <hip/hip_bf16.h>
#include <stdint.h>

#define NNODES 10000
#define NEDGES 320000
#define DIM    256
#define KTOT   512
#define LN_EPS 1e-5f

typedef __attribute__((ext_vector_type(4))) float f32x4;
typedef __attribute__((ext_vector_type(8))) short bf16x8;

__device__ __forceinline__ ushort f2bf(float f) {
    union { float f; uint32_t u; } v; v.f = f;
    uint32_t r = v.u + 0x7fffu + ((v.u >> 16) & 1u);   // RNE
    return (ushort)(r >> 16);
}
__device__ __forceinline__ float bf2f(ushort u) {
    union { float f; uint32_t u; } v; v.u = ((uint32_t)u) << 16;
    return v.f;
}

// cast x -> bf16 (float4 -> ushort4); also zeroes cnt[] (first 2560 threads)
__global__ void prep_cast(const float* __restrict__ src, ushort* __restrict__ dst,
                          int n4, int4* __restrict__ cntz) {
    int i = blockIdx.x * blockDim.x + threadIdx.x;
    if (i < 2560) cntz[i] = (int4){0, 0, 0, 0};       // 10240 ints
    if (i >= n4) return;
    float4 v = reinterpret_cast<const float4*>(src)[i];
    ushort4 o;
    o.x = f2bf(v.x); o.y = f2bf(v.y); o.z = f2bf(v.z); o.w = f2bf(v.w);
    reinterpret_cast<ushort4*>(dst)[i] = o;
}

// Wcat: fragment-arranged bf16 for the U|V GEMM (K=256, N=512).
//   idx = kk*16384 + g*512 + kg*128 + ml*8 + j ; k = kk*32+kg*8+j ; n = g*16+ml
//   n<256 -> W_msg[k][n] (U / src half) ; n>=256 -> W_msg[k+256][n-256] (V / dst half)
// Wua: node-update W (K=512, N=256):
//   idx = kk*8192 + nt*512 + kg*128 + ml*8 + j = W_upd[kk*32+kg*8+j][nt*16+ml]
__global__ void prep_wt(const float* __restrict__ Wm, const float* __restrict__ Wu,
                        ushort* __restrict__ Wcat, ushort* __restrict__ Wua) {
    int tid = blockIdx.x * blockDim.x + threadIdx.x;   // 262144 threads
    if (tid < 131072) {
        int kk  = tid >> 14;
        int rem = tid & 16383;
        int g   = rem >> 9;
        int kg  = (rem >> 7) & 3;
        int ml  = (rem >> 3) & 15;
        int j   = rem & 7;
        int k = kk * 32 + kg * 8 + j;
        int n = g * 16 + ml;
        float v = (n < 256) ? Wm[k * DIM + n] : Wm[(k + 256) * DIM + (n - 256)];
        Wcat[tid] = f2bf(v);
    } else {
        int rem = tid - 131072;
        int kk  = rem >> 13;
        int nt  = (rem >> 9) & 15;
        int kg  = (rem >> 7) & 3;
        int ml  = (rem >> 3) & 15;
        int j   = rem & 7;
        int k = kk * 32 + kg * 8 + j;
        int n = nt * 16 + ml;
        Wua[rem] = f2bf(Wu[k * DIM + n]);
    }
}

// ---- counting sort (CSR build) by destination ----
__global__ void hist_k(const int* __restrict__ eidx, int* __restrict__ cnt) {
    int e = blockIdx.x * blockDim.x + threadIdx.x;
    if (e < NEDGES) atomicAdd(&cnt[eidx[NEDGES + e]], 1);
}

__global__ void scan_k(const int* __restrict__ cnt, int* __restrict__ rptr,
                       int* __restrict__ cursor) {
    __shared__ int ts[256];
    int t = threadIdx.x;
    int base = t * 40;                       // 256*40 = 10240 >= NNODES
    int s = 0;
    for (int i = 0; i < 40; ++i) { int idx = base + i; if (idx < NNODES) s += cnt[idx]; }
    ts[t] = s;
    __syncthreads();
    int run = s;
    for (int off = 1; off < 256; off <<= 1) {   // Hillis-Steele inclusive scan
        int v = (t >= off) ? ts[t - off] : 0;
        __syncthreads();
        run += v;
        ts[t] = run;
        __syncthreads();
    }
    int o = run - s;                            // exclusive prefix
    for (int i = 0; i < 40; ++i) {
        int idx = base + i;
        if (idx < NNODES) { rptr[idx] = o; cursor[idx] = o; o += cnt[idx]; }
    }
}

// after this kernel, cursor[d] == rptr[d] + deg(d) == segment end
__global__ void scatter_k(const int* __restrict__ eidx, int* __restrict__ cursor,
                          int* __restrict__ srow) {
    int e = blockIdx.x * blockDim.x + threadIdx.x;
    if (e >= NEDGES) return;
    int d = eidx[NEDGES + e];
    int p = atomicAdd(&cursor[d], 1);
    srow[p] = eidx[e];
}

// ---- U|V GEMM: U = x @ W_msg[:256]  (bf16 out), V = x @ W_msg[256:] + b (fp32 out)
// 625 blocks x 256 thr (4 waves). Block = 16 nodes x 512 cols; wave wq owns
// cols [wq*128, +128) of the concatenated [U|V] output. K = 256 (x only).
__global__ __launch_bounds__(256)
void uv_gemm(const ushort* __restrict__ xb, const ushort* __restrict__ Wcat,
             const float* __restrict__ bmsg, ushort* __restrict__ Ub,
             float* __restrict__ Vf) {
    const int wq   = threadIdx.x >> 6;
    const int lane = threadIdx.x & 63;
    const int ml = lane & 15, kg = lane >> 4;
    const int nb = blockIdx.x * 16;
    const uint arow = (uint)(nb + ml) * DIM;

    f32x4 acc[8];
#pragma unroll
    for (int nt = 0; nt < 8; ++nt) acc[nt] = (f32x4){0.f, 0.f, 0.f, 0.f};

#pragma unroll
    for (int kk = 0; kk < 8; ++kk) {
        bf16x8 a = *reinterpret_cast<const bf16x8*>(xb + arow + kk * 32 + kg * 8);
#pragma unroll
        for (int nt = 0; nt < 8; ++nt) {
            bf16x8 b = *reinterpret_cast<const bf16x8*>(Wcat + kk * 16384 + (wq * 8 + nt) * 512 + lane * 8);
            acc[nt] = __builtin_amdgcn_mfma_f32_16x16x32_bf16(a, b, acc[nt], 0, 0, 0);
        }
    }

    if (wq < 2) {                                   // U half: bf16
#pragma unroll
        for (int nt = 0; nt < 8; ++nt) {
            const int col = wq * 128 + nt * 16 + ml;
#pragma unroll
            for (int i = 0; i < 4; ++i)
                Ub[(size_t)(nb + kg * 4 + i) * 256 + col] = f2bf(acc[nt][i]);
        }
    } else {                                        // V half: fp32, bias folded in
#pragma unroll
        for (int nt = 0; nt < 8; ++nt) {
            const int col = (wq - 2) * 128 + nt * 16 + ml;
            const float bb = bmsg[col];
#pragma unroll
            for (int i = 0; i < 4; ++i)
                Vf[(size_t)(nb + kg * 4 + i) * 256 + col] = acc[nt][i] + bb;
        }
    }
}

// ---- edge combine (CSR, atomic-free): agg[d] = sum_{e: dst=d} relu(U[src_e] + V[d])
// One wave per dst node; 4 nodes per 256-thr block; lane owns 4 columns.
// Plain float4 store per node (deg-0 nodes write zeros -> no agg memset needed).
__global__ __launch_bounds__(256)
void edge_combine(const ushort* __restrict__ Ub, const float* __restrict__ Vf,
                  const int* __restrict__ srow, const int* __restrict__ rptr,
                  const int* __restrict__ rend, float* __restrict__ agg) {
    const int wave = threadIdx.x >> 6, lane = threadIdx.x & 63;
    const int d = blockIdx.x * 4 + wave;          // 2500 blocks x 4 = 10000
    const int c0 = lane * 4;

    const int beg = rptr[d], end = rend[d];
    const float4 vc = *reinterpret_cast<const float4*>(&Vf[(size_t)d * 256 + c0]);
    float4 s = {0.f, 0.f, 0.f, 0.f};

    int i = beg;
    for (; i + 4 <= end; i += 4) {
        int s0 = srow[i], s1 = srow[i + 1], s2 = srow[i + 2], s3 = srow[i + 3];
        ushort4 u0 = *reinterpret_cast<const ushort4*>(&Ub[(size_t)s0 * 256 + c0]);
        ushort4 u1 = *reinterpret_cast<const ushort4*>(&Ub[(size_t)s1 * 256 + c0]);
        ushort4 u2 = *reinterpret_cast<const ushort4*>(&Ub[(size_t)s2 * 256 + c0]);
        ushort4 u3 = *reinterpret_cast<const ushort4*>(&Ub[(size_t)s3 * 256 + c0]);
#define ACC(U) do { \
        s.x += fmaxf(bf2f(U.x) + vc.x, 0.f); \
        s.y += fmaxf(bf2f(U.y) + vc.y, 0.f); \
        s.z += fmaxf(bf2f(U.z) + vc.z, 0.f); \
        s.w += fmaxf(bf2f(U.w) + vc.w, 0.f); } while (0)
        ACC(u0); ACC(u1); ACC(u2); ACC(u3);
    }
    for (; i < end; ++i) {
        int sr = srow[i];
        ushort4 u = *reinterpret_cast<const ushort4*>(&Ub[(size_t)sr * 256 + c0]);
        ACC(u);
    }
#undef ACC
    *reinterpret_cast<float4*>(&agg[(size_t)d * 256 + c0]) = s;
}

// ---- node update GEMM + bias + relu + LayerNorm ----
// 625 blocks x 256 thr (4 waves). Block = 16 nodes x 256 cols; wave wq handles
// cols [wq*64, +64) over full K=512. LN partials combined via tiny LDS exchange.
__global__ __launch_bounds__(256)
void node_gemm_ln(const ushort* __restrict__ xb, const float* __restrict__ agg,
                  const ushort* __restrict__ Wua, const float* __restrict__ bupd,
                  const float* __restrict__ gamma, const float* __restrict__ beta,
                  float* __restrict__ out) {
    __shared__ float pS[16][4][2];     // [node][wave][sum,ssq]

    const int wq   = threadIdx.x >> 6;
    const int lane = threadIdx.x & 63;
    const int ml = lane & 15, kg = lane >> 4;
    const int nb = blockIdx.x * 16;
    const uint arow = (uint)(nb + ml) * DIM;          // 625*16 = 10000 exactly

    f32x4 acc[4];
#pragma unroll
    for (int nt = 0; nt < 4; ++nt) acc[nt] = (f32x4){0.f, 0.f, 0.f, 0.f};

#pragma unroll
    for (int kk = 0; kk < 8; ++kk) {                  // k in [0,256): A = xb
        bf16x8 a = *reinterpret_cast<const bf16x8*>(xb + arow + kk * 32 + kg * 8);
#pragma unroll
        for (int nt = 0; nt < 4; ++nt) {
            bf16x8 b = *reinterpret_cast<const bf16x8*>(Wua + kk * 8192 + (wq * 4 + nt) * 512 + lane * 8);
            acc[nt] = __builtin_amdgcn_mfma_f32_16x16x32_bf16(a, b, acc[nt], 0, 0, 0);
        }
    }
#pragma unroll
    for (int kk = 0; kk < 8; ++kk) {                  // k in [256,512): A = agg (fp32)
        float4 f0 = *reinterpret_cast<const float4*>(agg + arow + kk * 32 + kg * 8);
        float4 f1 = *reinterpret_cast<const float4*>(agg + arow + kk * 32 + kg * 8 + 4);
        union { bf16x8 v; __hip_bfloat162 h2[4]; } u;
        u.h2[0] = __float22bfloat162_rn(make_float2(f0.x, f0.y));
        u.h2[1] = __float22bfloat162_rn(make_float2(f0.z, f0.w));
        u.h2[2] = __float22bfloat162_rn(make_float2(f1.x, f1.y));
        u.h2[3] = __float22bfloat162_rn(make_float2(f1.z, f1.w));
#pragma unroll
        for (int nt = 0; nt < 4; ++nt) {
            bf16x8 b = *reinterpret_cast<const bf16x8*>(Wua + 65536 + kk * 8192 + (wq * 4 + nt) * 512 + lane * 8);
            acc[nt] = __builtin_amdgcn_mfma_f32_16x16x32_bf16(u.v, b, acc[nt], 0, 0, 0);
        }
    }

    // bias + relu + per-wave partial sums (this wave's 64 cols)
    float sum[4] = {0.f, 0.f, 0.f, 0.f}, ssq[4] = {0.f, 0.f, 0.f, 0.f};
#pragma unroll
    for (int nt = 0; nt < 4; ++nt) {
        const float bb = bupd[wq * 64 + nt * 16 + ml];
#pragma unroll
        for (int i = 0; i < 4; ++i) {
            float v = acc[nt][i] + bb;
            v = v > 0.f ? v : 0.f;
            acc[nt][i] = v;
            sum[i] += v;
            ssq[i] += v * v;
        }
    }
#pragma unroll
    for (int m = 1; m < 16; m <<= 1) {
#pragma unroll
        for (int i = 0; i < 4; ++i) {
            sum[i] += __shfl_xor(sum[i], m);
            ssq[i] += __shfl_xor(ssq[i], m);
        }
    }
    if (ml == 0) {
#pragma unroll
        for (int i = 0; i < 4; ++i) {
            pS[kg * 4 + i][wq][0] = sum[i];
            pS[kg * 4 + i][wq][1] = ssq[i];
        }
    }
    __syncthreads();

    float mu[4], rs[4];
#pragma unroll
    for (int i = 0; i < 4; ++i) {
        int r = kg * 4 + i;
        float S = pS[r][0][0] + pS[r][1][0] + pS[r][2][0] + pS[r][3][0];
        float Q = pS[r][0][1] + pS[r][1][1] + pS[r][2][1] + pS[r][3][1];
        float m = S * (1.f / 256.f);
        float var = Q * (1.f / 256.f) - m * m;
        mu[i] = m;
        rs[i] = rsqrtf(var + LN_EPS);
    }
#pragma unroll
    for (int nt = 0; nt < 4; ++nt) {
        const int cc = wq * 64 + nt * 16 + ml;
        const float g = gamma[cc], be = beta[cc];
#pragma unroll
        for (int i = 0; i < 4; ++i) {
            const int node = nb + kg * 4 + i;
            out[(size_t)node * DIM + cc] = (acc[nt][i] - mu[i]) * rs[i] * g + be;
        }
    }
}

extern "C" void kernel_launch(void* const* d_in, const int* in_sizes, int n_in,
                              void* d_out, int out_size, void* d_ws, size_t ws_size,
                              hipStream_t stream) {
    const float* x    = (const float*)d_in[0];
    const int*   eidx = (const int*)  d_in[1];
    const float* Wm   = (const float*)d_in[2];
    const float* bm   = (const float*)d_in[3];
    const float* Wu   = (const float*)d_in[4];
    const float* bu   = (const float*)d_in[5];
    const float* gam  = (const float*)d_in[6];
    const float* bet  = (const float*)d_in[7];
    float* out = (float*)d_out;

    char* ws = (char*)d_ws;
    float*  agg    = (float*) (ws);                    // 10,240,000 B
    ushort* xb     = (ushort*)(ws + 10240000);         //  5,120,000 B
    ushort* Ub     = (ushort*)(ws + 15360000);         //  5,120,000 B
    float*  Vf     = (float*) (ws + 20480000);         // 10,240,000 B
    ushort* Wcat   = (ushort*)(ws + 30720000);         //    262,144 B
    ushort* Wua    = (ushort*)(ws + 30982144);         //    262,144 B
    int*    cnt    = (int*)   (ws + 31244288);         //     40,960 B
    int*    rptr   = (int*)   (ws + 31285248);         //     40,960 B
    int*    cursor = (int*)   (ws + 31326208);         //     40,960 B
    int*    srow   = (int*)   (ws + 31367168);         //  1,280,000 B (end ~32.6 MB)

    prep_cast<<<(NNODES * DIM / 4 + 255) / 256, 256, 0, stream>>>(x, xb, NNODES * DIM / 4, (int4*)cnt);
    prep_wt<<<(2 * KTOT * DIM) / 256, 256, 0, stream>>>(Wm, Wu, Wcat, Wua);
    hist_k<<<(NEDGES + 255) / 256, 256, 0, stream>>>(eidx, cnt);
    scan_k<<<1, 256, 0, stream>>>(cnt, rptr, cursor);
    scatter_k<<<(NEDGES + 255) / 256, 256, 0, stream>>>(eidx, cursor, srow);
    uv_gemm<<<NNODES / 16, 256, 0, stream>>>(xb, Wcat, bm, Ub, Vf);
    edge_combine<<<NNODES / 4, 256, 0, stream>>>(Ub, Vf, srow, rptr, cursor, agg);
    node_gemm_ln<<<NNODES / 16, 256, 0, stream>>>(xb, agg, Wua, bu, gam, bet, out);
}

// Round 10
// 112.801 us; speedup vs baseline: 2.1845x; 1.2244x over previous
//
#include <hip/hip_runtime.h>
#include <hip/hip_bf16.h>
#include <stdint.h>

#define NNODES 10000
#define NEDGES 320000
#define DIM    256
#define KTOT   512
#define LN_EPS 1e-5f

typedef __attribute__((ext_vector_type(4))) float f32x4;
typedef __attribute__((ext_vector_type(8))) short bf16x8;

__device__ __forceinline__ ushort f2bf(float f) {
    union { float f; uint32_t u; } v; v.f = f;
    uint32_t r = v.u + 0x7fffu + ((v.u >> 16) & 1u);   // RNE
    return (ushort)(r >> 16);
}
__device__ __forceinline__ float bf2f(ushort u) {
    union { float f; uint32_t u; } v; v.u = ((uint32_t)u) << 16;
    return v.f;
}

// ---- K1: prep — cast x->bf16, zero cnt, fragment-arrange both W matrices ----
// Wcat (U|V GEMM, K=256, N=512): idx = kk*16384 + g*512 + kg*128 + ml*8 + j
//   n=g*16+ml; n<256 -> W_msg[k][n] (U); else W_msg[k+256][n-256] (V)
// Wua (node GEMM, K=512, N=256): idx = kk*8192 + nt*512 + kg*128 + ml*8 + j
__global__ __launch_bounds__(256)
void prep_all(const float* __restrict__ x, const float* __restrict__ Wm,
              const float* __restrict__ Wu, ushort* __restrict__ xb,
              ushort* __restrict__ Wcat, ushort* __restrict__ Wua,
              int4* __restrict__ cntz) {
    int tid = blockIdx.x * 256 + threadIdx.x;          // 3524*256 = 902144
    if (tid < 2560) cntz[tid] = (int4){0, 0, 0, 0};    // 10240 ints
    if (tid < 640000) {                                // x cast, one float4 each
        float4 v = reinterpret_cast<const float4*>(x)[tid];
        ushort4 o;
        o.x = f2bf(v.x); o.y = f2bf(v.y); o.z = f2bf(v.z); o.w = f2bf(v.w);
        reinterpret_cast<ushort4*>(xb)[tid] = o;
    } else {
        int t = tid - 640000;                          // < 262144
        if (t < 131072) {
            int kk  = t >> 14;
            int rem = t & 16383;
            int g   = rem >> 9;
            int kg  = (rem >> 7) & 3;
            int ml  = (rem >> 3) & 15;
            int j   = rem & 7;
            int k = kk * 32 + kg * 8 + j;
            int n = g * 16 + ml;
            float v = (n < 256) ? Wm[k * DIM + n] : Wm[(k + 256) * DIM + (n - 256)];
            Wcat[t] = f2bf(v);
        } else {
            int rem = t - 131072;
            int kk  = rem >> 13;
            int nt  = (rem >> 9) & 15;
            int kg  = (rem >> 7) & 3;
            int ml  = (rem >> 3) & 15;
            int j   = rem & 7;
            int k = kk * 32 + kg * 8 + j;
            int n = nt * 16 + ml;
            Wua[rem] = f2bf(Wu[k * DIM + n]);
        }
    }
}

// ---- K2: histogram of destinations ----
__global__ void hist_k(const int* __restrict__ eidx, int* __restrict__ cnt) {
    int e = blockIdx.x * blockDim.x + threadIdx.x;
    if (e < NEDGES) atomicAdd(&cnt[eidx[NEDGES + e]], 1);
}

// ---- K3: exclusive scan (1024 threads, 10 nodes each) ----
__global__ __launch_bounds__(1024)
void scan_k(const int* __restrict__ cnt, int* __restrict__ rptr,
            int* __restrict__ cursor) {
    __shared__ int ts[1024];
    int t = threadIdx.x;
    int base = t * 10;                       // 1024*10 = 10240 >= NNODES
    int s = 0;
    for (int i = 0; i < 10; ++i) { int idx = base + i; if (idx < NNODES) s += cnt[idx]; }
    ts[t] = s;
    __syncthreads();
    int run = s;
    for (int off = 1; off < 1024; off <<= 1) {
        int v = (t >= off) ? ts[t - off] : 0;
        __syncthreads();
        run += v;
        ts[t] = run;
        __syncthreads();
    }
    int o = run - s;                         // exclusive prefix
    for (int i = 0; i < 10; ++i) {
        int idx = base + i;
        if (idx < NNODES) { rptr[idx] = o; cursor[idx] = o; o += cnt[idx]; }
    }
}

// ---- K4: scatter (CSR fill) in blocks [0,1250) ∥ U|V GEMM in [1250,1875) ----
__global__ __launch_bounds__(256)
void scatter_uv(const int* __restrict__ eidx, int* __restrict__ cursor,
                int* __restrict__ srow, const ushort* __restrict__ xb,
                const ushort* __restrict__ Wcat, const float* __restrict__ bmsg,
                ushort* __restrict__ Ub, float* __restrict__ Vf) {
    if (blockIdx.x < 1250) {
        int e = blockIdx.x * 256 + threadIdx.x;        // 1250*256 = 320000 exact
        int d = eidx[NEDGES + e];
        int p = atomicAdd(&cursor[d], 1);
        srow[p] = eidx[e];
        return;
    }
    // U = x @ W_msg[:256] (bf16), V = x @ W_msg[256:] + b (fp32)
    const int wq   = threadIdx.x >> 6;
    const int lane = threadIdx.x & 63;
    const int ml = lane & 15, kg = lane >> 4;
    const int nb = (blockIdx.x - 1250) * 16;
    const uint arow = (uint)(nb + ml) * DIM;

    f32x4 acc[8];
#pragma unroll
    for (int nt = 0; nt < 8; ++nt) acc[nt] = (f32x4){0.f, 0.f, 0.f, 0.f};

#pragma unroll
    for (int kk = 0; kk < 8; ++kk) {
        bf16x8 a = *reinterpret_cast<const bf16x8*>(xb + arow + kk * 32 + kg * 8);
#pragma unroll
        for (int nt = 0; nt < 8; ++nt) {
            bf16x8 b = *reinterpret_cast<const bf16x8*>(Wcat + kk * 16384 + (wq * 8 + nt) * 512 + lane * 8);
            acc[nt] = __builtin_amdgcn_mfma_f32_16x16x32_bf16(a, b, acc[nt], 0, 0, 0);
        }
    }

    if (wq < 2) {                                   // U half: bf16
#pragma unroll
        for (int nt = 0; nt < 8; ++nt) {
            const int col = wq * 128 + nt * 16 + ml;
#pragma unroll
            for (int i = 0; i < 4; ++i)
                Ub[(size_t)(nb + kg * 4 + i) * 256 + col] = f2bf(acc[nt][i]);
        }
    } else {                                        // V half: fp32, bias folded
#pragma unroll
        for (int nt = 0; nt < 8; ++nt) {
            const int col = (wq - 2) * 128 + nt * 16 + ml;
            const float bb = bmsg[col];
#pragma unroll
            for (int i = 0; i < 4; ++i)
                Vf[(size_t)(nb + kg * 4 + i) * 256 + col] = acc[nt][i] + bb;
        }
    }
}

// ---- K5: fused edge-combine + node GEMM + LayerNorm ----
// 625 blocks x 512 thr (8 waves) = 16 nodes/block.
// Phase A: wave w reduces nodes nb+2w, nb+2w+1: lane owns 4 cols;
//          agg row -> LDS (16x260 f32, no global round-trip, no memset).
// Phase B: 16x256 update GEMM; k<256 A from xb, k>=256 A from LDS; LN fused.
__global__ __launch_bounds__(512)
void edge_node(const ushort* __restrict__ Ub, const float* __restrict__ Vf,
               const int* __restrict__ srow, const int* __restrict__ rptr,
               const int* __restrict__ rend, const ushort* __restrict__ xb,
               const ushort* __restrict__ Wua, const float* __restrict__ bupd,
               const float* __restrict__ gamma, const float* __restrict__ beta,
               float* __restrict__ out) {
    __shared__ float aggS[16][260];     // +4 pad: 2-way banks max
    __shared__ float pS[16][8][2];      // LN partials [node][wave][sum,ssq]

    const int tid  = threadIdx.x;
    const int wave = tid >> 6, lane = tid & 63;
    const int nb = blockIdx.x * 16;
    const int c0 = lane * 4;

    // ---- Phase A: segmented reduce over CSR ----
#pragma unroll
    for (int nn = 0; nn < 2; ++nn) {
        const int d = nb + wave * 2 + nn;
        const int beg = rptr[d], end = rend[d];
        const float4 vc = *reinterpret_cast<const float4*>(&Vf[(size_t)d * 256 + c0]);
        float4 s = {0.f, 0.f, 0.f, 0.f};
        int i = beg;
#define ACC(U) do { \
        s.x += fmaxf(bf2f(U.x) + vc.x, 0.f); \
        s.y += fmaxf(bf2f(U.y) + vc.y, 0.f); \
        s.z += fmaxf(bf2f(U.z) + vc.z, 0.f); \
        s.w += fmaxf(bf2f(U.w) + vc.w, 0.f); } while (0)
        for (; i + 4 <= end; i += 4) {
            int s0 = srow[i], s1 = srow[i + 1], s2 = srow[i + 2], s3 = srow[i + 3];
            ushort4 u0 = *reinterpret_cast<const ushort4*>(&Ub[(size_t)s0 * 256 + c0]);
            ushort4 u1 = *reinterpret_cast<const ushort4*>(&Ub[(size_t)s1 * 256 + c0]);
            ushort4 u2 = *reinterpret_cast<const ushort4*>(&Ub[(size_t)s2 * 256 + c0]);
            ushort4 u3 = *reinterpret_cast<const ushort4*>(&Ub[(size_t)s3 * 256 + c0]);
            ACC(u0); ACC(u1); ACC(u2); ACC(u3);
        }
        for (; i < end; ++i) {
            int sr = srow[i];
            ushort4 u = *reinterpret_cast<const ushort4*>(&Ub[(size_t)sr * 256 + c0]);
            ACC(u);
        }
#undef ACC
        *reinterpret_cast<float4*>(&aggS[wave * 2 + nn][c0]) = s;
    }
    __syncthreads();

    // ---- Phase B: update GEMM (wave wq owns 32 cols) ----
    const int ml = lane & 15, kg = lane >> 4, wq = wave;
    const uint arow = (uint)(nb + ml) * DIM;

    f32x4 acc[2];
    acc[0] = (f32x4){0.f, 0.f, 0.f, 0.f};
    acc[1] = (f32x4){0.f, 0.f, 0.f, 0.f};

#pragma unroll
    for (int kk = 0; kk < 8; ++kk) {                  // k in [0,256): A = xb
        bf16x8 a = *reinterpret_cast<const bf16x8*>(xb + arow + kk * 32 + kg * 8);
#pragma unroll
        for (int nt = 0; nt < 2; ++nt) {
            bf16x8 b = *reinterpret_cast<const bf16x8*>(Wua + kk * 8192 + (wq * 2 + nt) * 512 + lane * 8);
            acc[nt] = __builtin_amdgcn_mfma_f32_16x16x32_bf16(a, b, acc[nt], 0, 0, 0);
        }
    }
#pragma unroll
    for (int kk = 0; kk < 8; ++kk) {                  // k in [256,512): A = aggS (LDS f32)
        float4 f0 = *reinterpret_cast<const float4*>(&aggS[ml][kk * 32 + kg * 8]);
        float4 f1 = *reinterpret_cast<const float4*>(&aggS[ml][kk * 32 + kg * 8 + 4]);
        union { bf16x8 v; __hip_bfloat162 h2[4]; } u;
        u.h2[0] = __float22bfloat162_rn(make_float2(f0.x, f0.y));
        u.h2[1] = __float22bfloat162_rn(make_float2(f0.z, f0.w));
        u.h2[2] = __float22bfloat162_rn(make_float2(f1.x, f1.y));
        u.h2[3] = __float22bfloat162_rn(make_float2(f1.z, f1.w));
#pragma unroll
        for (int nt = 0; nt < 2; ++nt) {
            bf16x8 b = *reinterpret_cast<const bf16x8*>(Wua + 65536 + kk * 8192 + (wq * 2 + nt) * 512 + lane * 8);
            acc[nt] = __builtin_amdgcn_mfma_f32_16x16x32_bf16(u.v, b, acc[nt], 0, 0, 0);
        }
    }

    // bias + relu + per-wave LN partials (32 cols per wave)
    float sum[4] = {0.f, 0.f, 0.f, 0.f}, ssq[4] = {0.f, 0.f, 0.f, 0.f};
#pragma unroll
    for (int nt = 0; nt < 2; ++nt) {
        const float bb = bupd[(wq * 2 + nt) * 16 + ml];
#pragma unroll
        for (int i = 0; i < 4; ++i) {
            float v = acc[nt][i] + bb;
            v = v > 0.f ? v : 0.f;
            acc[nt][i] = v;
            sum[i] += v;
            ssq[i] += v * v;
        }
    }
#pragma unroll
    for (int m = 1; m < 16; m <<= 1) {
#pragma unroll
        for (int i = 0; i < 4; ++i) {
            sum[i] += __shfl_xor(sum[i], m);
            ssq[i] += __shfl_xor(ssq[i], m);
        }
    }
    if (ml == 0) {
#pragma unroll
        for (int i = 0; i < 4; ++i) {
            pS[kg * 4 + i][wq][0] = sum[i];
            pS[kg * 4 + i][wq][1] = ssq[i];
        }
    }
    __syncthreads();

    float mu[4], rs[4];
#pragma unroll
    for (int i = 0; i < 4; ++i) {
        int r = kg * 4 + i;
        float S = 0.f, Q = 0.f;
#pragma unroll
        for (int w = 0; w < 8; ++w) { S += pS[r][w][0]; Q += pS[r][w][1]; }
        float m = S * (1.f / 256.f);
        float var = Q * (1.f / 256.f) - m * m;
        mu[i] = m;
        rs[i] = rsqrtf(var + LN_EPS);
    }
#pragma unroll
    for (int nt = 0; nt < 2; ++nt) {
        const int cc = (wq * 2 + nt) * 16 + ml;
        const float g = gamma[cc], be = beta[cc];
#pragma unroll
        for (int i = 0; i < 4; ++i) {
            const int node = nb + kg * 4 + i;
            out[(size_t)node * DIM + cc] = (acc[nt][i] - mu[i]) * rs[i] * g + be;
        }
    }
}

extern "C" void kernel_launch(void* const* d_in, const int* in_sizes, int n_in,
                              void* d_out, int out_size, void* d_ws, size_t ws_size,
                              hipStream_t stream) {
    const float* x    = (const float*)d_in[0];
    const int*   eidx = (const int*)  d_in[1];
    const float* Wm   = (const float*)d_in[2];
    const float* bm   = (const float*)d_in[3];
    const float* Wu   = (const float*)d_in[4];
    const float* bu   = (const float*)d_in[5];
    const float* gam  = (const float*)d_in[6];
    const float* bet  = (const float*)d_in[7];
    float* out = (float*)d_out;

    char* ws = (char*)d_ws;
    ushort* xb     = (ushort*)(ws);                    //  5,120,000 B
    ushort* Ub     = (ushort*)(ws +  5120000);         //  5,120,000 B
    float*  Vf     = (float*) (ws + 10240000);         // 10,240,000 B
    ushort* Wcat   = (ushort*)(ws + 20480000);         //    262,144 B
    ushort* Wua    = (ushort*)(ws + 20742144);         //    262,144 B
    int*    cnt    = (int*)   (ws + 21004288);         //     40,960 B
    int*    rptr   = (int*)   (ws + 21045248);         //     40,960 B
    int*    cursor = (int*)   (ws + 21086208);         //     40,960 B
    int*    srow   = (int*)   (ws + 21127168);         //  1,280,000 B (end ~22.4 MB)

    prep_all<<<3524, 256, 0, stream>>>(x, Wm, Wu, xb, Wcat, Wua, (int4*)cnt);
    hist_k<<<1250, 256, 0, stream>>>(eidx, cnt);
    scan_k<<<1, 1024, 0, stream>>>(cnt, rptr, cursor);
    scatter_uv<<<1875, 256, 0, stream>>>(eidx, cursor, srow, xb, Wcat, bm, Ub, Vf);
    edge_node<<<625, 512, 0, stream>>>(Ub, Vf, srow, rptr, cursor, xb, Wua, bu, gam, bet, out);
}

// Round 11
// 83.661 us; speedup vs baseline: 2.9455x; 1.3483x over previous
//
#include <hip/hip_runtime.h>
#include <hip/hip_bf16.h>
#include <stdint.h>

#define NNODES 10000
#define NEDGES 320000
#define DIM    256
#define KTOT   512
#define LN_EPS 1e-5f
#define BCAP   96     // per-node bucket capacity (max degree; P(exceed) ~ 1e-20)

typedef __attribute__((ext_vector_type(4))) float f32x4;
typedef __attribute__((ext_vector_type(8))) short bf16x8;

__device__ __forceinline__ ushort f2bf(float f) {
    union { float f; uint32_t u; } v; v.f = f;
    uint32_t r = v.u + 0x7fffu + ((v.u >> 16) & 1u);   // RNE
    return (ushort)(r >> 16);
}
__device__ __forceinline__ float bf2f(ushort u) {
    union { float f; uint32_t u; } v; v.u = ((uint32_t)u) << 16;
    return v.f;
}

// ---- K1: prep — cast x->bf16, zero cnt, fragment-arrange both W matrices ----
// Wcat (U|V GEMM, K=256, N=512): idx = kk*16384 + g*512 + kg*128 + ml*8 + j
//   n=g*16+ml; n<256 -> W_msg[k][n] (U); else W_msg[k+256][n-256] (V)
// Wua (node GEMM, K=512, N=256): idx = kk*8192 + nt*512 + kg*128 + ml*8 + j
__global__ __launch_bounds__(256)
void prep_all(const float* __restrict__ x, const float* __restrict__ Wm,
              const float* __restrict__ Wu, ushort* __restrict__ xb,
              ushort* __restrict__ Wcat, ushort* __restrict__ Wua,
              int4* __restrict__ cntz) {
    int tid = blockIdx.x * 256 + threadIdx.x;          // 3524*256 = 902144
    if (tid < 2560) cntz[tid] = (int4){0, 0, 0, 0};    // 10240 ints >= NNODES
    if (tid < 640000) {                                // x cast, one float4 each
        float4 v = reinterpret_cast<const float4*>(x)[tid];
        ushort4 o;
        o.x = f2bf(v.x); o.y = f2bf(v.y); o.z = f2bf(v.z); o.w = f2bf(v.w);
        reinterpret_cast<ushort4*>(xb)[tid] = o;
    } else {
        int t = tid - 640000;                          // < 262144
        if (t < 131072) {
            int kk  = t >> 14;
            int rem = t & 16383;
            int g   = rem >> 9;
            int kg  = (rem >> 7) & 3;
            int ml  = (rem >> 3) & 15;
            int j   = rem & 7;
            int k = kk * 32 + kg * 8 + j;
            int n = g * 16 + ml;
            float v = (n < 256) ? Wm[k * DIM + n] : Wm[(k + 256) * DIM + (n - 256)];
            Wcat[t] = f2bf(v);
        } else {
            int rem = t - 131072;
            int kk  = rem >> 13;
            int nt  = (rem >> 9) & 15;
            int kg  = (rem >> 7) & 3;
            int ml  = (rem >> 3) & 15;
            int j   = rem & 7;
            int k = kk * 32 + kg * 8 + j;
            int n = nt * 16 + ml;
            Wua[rem] = f2bf(Wu[k * DIM + n]);
        }
    }
}

// ---- K2: bucket scatter (blocks [0,1250)) ∥ U|V GEMM (blocks [1250,1875)) ----
// Scatter: srow[d*BCAP + p] = src, p = atomicAdd(cnt[d]) -- cnt becomes degree.
__global__ __launch_bounds__(256)
void scatter_uv(const int* __restrict__ eidx, int* __restrict__ cnt,
                int* __restrict__ srow, const ushort* __restrict__ xb,
                const ushort* __restrict__ Wcat, const float* __restrict__ bmsg,
                ushort* __restrict__ Ub, float* __restrict__ Vf) {
    if (blockIdx.x < 1250) {
        int e = blockIdx.x * 256 + threadIdx.x;        // 1250*256 = 320000 exact
        int d = eidx[NEDGES + e];
        int p = atomicAdd(&cnt[d], 1);
        if (p < BCAP) srow[d * BCAP + p] = eidx[e];
        return;
    }
    // U = x @ W_msg[:256] (bf16), V = x @ W_msg[256:] + b (fp32)
    const int wq   = threadIdx.x >> 6;
    const int lane = threadIdx.x & 63;
    const int ml = lane & 15, kg = lane >> 4;
    const int nb = (blockIdx.x - 1250) * 16;
    const uint arow = (uint)(nb + ml) * DIM;

    f32x4 acc[8];
#pragma unroll
    for (int nt = 0; nt < 8; ++nt) acc[nt] = (f32x4){0.f, 0.f, 0.f, 0.f};

#pragma unroll
    for (int kk = 0; kk < 8; ++kk) {
        bf16x8 a = *reinterpret_cast<const bf16x8*>(xb + arow + kk * 32 + kg * 8);
#pragma unroll
        for (int nt = 0; nt < 8; ++nt) {
            bf16x8 b = *reinterpret_cast<const bf16x8*>(Wcat + kk * 16384 + (wq * 8 + nt) * 512 + lane * 8);
            acc[nt] = __builtin_amdgcn_mfma_f32_16x16x32_bf16(a, b, acc[nt], 0, 0, 0);
        }
    }

    if (wq < 2) {                                   // U half: bf16
#pragma unroll
        for (int nt = 0; nt < 8; ++nt) {
            const int col = wq * 128 + nt * 16 + ml;
#pragma unroll
            for (int i = 0; i < 4; ++i)
                Ub[(size_t)(nb + kg * 4 + i) * 256 + col] = f2bf(acc[nt][i]);
        }
    } else {                                        // V half: fp32, bias folded
#pragma unroll
        for (int nt = 0; nt < 8; ++nt) {
            const int col = (wq - 2) * 128 + nt * 16 + ml;
            const float bb = bmsg[col];
#pragma unroll
            for (int i = 0; i < 4; ++i)
                Vf[(size_t)(nb + kg * 4 + i) * 256 + col] = acc[nt][i] + bb;
        }
    }
}

// ---- K3: fused edge-combine + node GEMM + LayerNorm ----
// 625 blocks x 512 thr (8 waves) = 16 nodes/block.
// Phase A: wave w reduces nodes nb+2w, nb+2w+1. Lane owns 8 cols (16B U loads);
//          the two 32-lane halves split each edge list (even/odd indices) and
//          are combined with one shfl_xor(32). agg row -> LDS.
// Phase B: 16x256 update GEMM; k<256 A from xb, k>=256 A from LDS; LN fused.
__global__ __launch_bounds__(512)
void edge_node(const ushort* __restrict__ Ub, const float* __restrict__ Vf,
               const int* __restrict__ srow, const int* __restrict__ cnt,
               const ushort* __restrict__ xb, const ushort* __restrict__ Wua,
               const float* __restrict__ bupd, const float* __restrict__ gamma,
               const float* __restrict__ beta, float* __restrict__ out) {
    __shared__ float aggS[16][260];     // +4 pad
    __shared__ float pS[16][8][2];      // LN partials [node][wave][sum,ssq]

    const int tid  = threadIdx.x;
    const int wave = tid >> 6, lane = tid & 63;
    const int nb = blockIdx.x * 16;
    const int el = lane >> 5;           // half id (edge-parity)
    const int cl = lane & 31;
    const int c0 = cl * 8;              // 8 cols owned

    // ---- Phase A ----
#pragma unroll
    for (int nn = 0; nn < 2; ++nn) {
        const int d = nb + wave * 2 + nn;
        int deg = cnt[d]; deg = deg < BCAP ? deg : BCAP;
        const int beg = d * BCAP;
        const float4 va = *reinterpret_cast<const float4*>(&Vf[(size_t)d * 256 + c0]);
        const float4 vb = *reinterpret_cast<const float4*>(&Vf[(size_t)d * 256 + c0 + 4]);
        float s[8];
#pragma unroll
        for (int j = 0; j < 8; ++j) s[j] = 0.f;

#define ACC8(U) do { \
        s[0] += fmaxf(bf2f((ushort)(U)[0]) + va.x, 0.f); \
        s[1] += fmaxf(bf2f((ushort)(U)[1]) + va.y, 0.f); \
        s[2] += fmaxf(bf2f((ushort)(U)[2]) + va.z, 0.f); \
        s[3] += fmaxf(bf2f((ushort)(U)[3]) + va.w, 0.f); \
        s[4] += fmaxf(bf2f((ushort)(U)[4]) + vb.x, 0.f); \
        s[5] += fmaxf(bf2f((ushort)(U)[5]) + vb.y, 0.f); \
        s[6] += fmaxf(bf2f((ushort)(U)[6]) + vb.z, 0.f); \
        s[7] += fmaxf(bf2f((ushort)(U)[7]) + vb.w, 0.f); } while (0)

        int i = el;                      // this half handles indices el, el+2, ...
        for (; i + 6 < deg; i += 8) {    // 4 rows in flight per half
            int r0 = srow[beg + i],     r1 = srow[beg + i + 2];
            int r2 = srow[beg + i + 4], r3 = srow[beg + i + 6];
            bf16x8 u0 = *reinterpret_cast<const bf16x8*>(&Ub[(size_t)r0 * 256 + c0]);
            bf16x8 u1 = *reinterpret_cast<const bf16x8*>(&Ub[(size_t)r1 * 256 + c0]);
            bf16x8 u2 = *reinterpret_cast<const bf16x8*>(&Ub[(size_t)r2 * 256 + c0]);
            bf16x8 u3 = *reinterpret_cast<const bf16x8*>(&Ub[(size_t)r3 * 256 + c0]);
            ACC8(u0); ACC8(u1); ACC8(u2); ACC8(u3);
        }
        for (; i < deg; i += 2) {
            int r = srow[beg + i];
            bf16x8 u = *reinterpret_cast<const bf16x8*>(&Ub[(size_t)r * 256 + c0]);
            ACC8(u);
        }
#undef ACC8
#pragma unroll
        for (int j = 0; j < 8; ++j) s[j] += __shfl_xor(s[j], 32);
        if (el == 0) {
            *reinterpret_cast<float4*>(&aggS[wave * 2 + nn][c0])     = (float4){s[0], s[1], s[2], s[3]};
            *reinterpret_cast<float4*>(&aggS[wave * 2 + nn][c0 + 4]) = (float4){s[4], s[5], s[6], s[7]};
        }
    }
    __syncthreads();

    // ---- Phase B: update GEMM (wave wq owns 32 cols) ----
    const int ml = lane & 15, kg = lane >> 4, wq = wave;
    const uint arow = (uint)(nb + ml) * DIM;

    f32x4 acc[2];
    acc[0] = (f32x4){0.f, 0.f, 0.f, 0.f};
    acc[1] = (f32x4){0.f, 0.f, 0.f, 0.f};

#pragma unroll
    for (int kk = 0; kk < 8; ++kk) {                  // k in [0,256): A = xb
        bf16x8 a = *reinterpret_cast<const bf16x8*>(xb + arow + kk * 32 + kg * 8);
#pragma unroll
        for (int nt = 0; nt < 2; ++nt) {
            bf16x8 b = *reinterpret_cast<const bf16x8*>(Wua + kk * 8192 + (wq * 2 + nt) * 512 + lane * 8);
            acc[nt] = __builtin_amdgcn_mfma_f32_16x16x32_bf16(a, b, acc[nt], 0, 0, 0);
        }
    }
#pragma unroll
    for (int kk = 0; kk < 8; ++kk) {                  // k in [256,512): A = aggS
        float4 f0 = *reinterpret_cast<const float4*>(&aggS[ml][kk * 32 + kg * 8]);
        float4 f1 = *reinterpret_cast<const float4*>(&aggS[ml][kk * 32 + kg * 8 + 4]);
        union { bf16x8 v; __hip_bfloat162 h2[4]; } u;
        u.h2[0] = __float22bfloat162_rn(make_float2(f0.x, f0.y));
        u.h2[1] = __float22bfloat162_rn(make_float2(f0.z, f0.w));
        u.h2[2] = __float22bfloat162_rn(make_float2(f1.x, f1.y));
        u.h2[3] = __float22bfloat162_rn(make_float2(f1.z, f1.w));
#pragma unroll
        for (int nt = 0; nt < 2; ++nt) {
            bf16x8 b = *reinterpret_cast<const bf16x8*>(Wua + 65536 + kk * 8192 + (wq * 2 + nt) * 512 + lane * 8);
            acc[nt] = __builtin_amdgcn_mfma_f32_16x16x32_bf16(u.v, b, acc[nt], 0, 0, 0);
        }
    }

    // bias + relu + per-wave LN partials (32 cols per wave)
    float sum[4] = {0.f, 0.f, 0.f, 0.f}, ssq[4] = {0.f, 0.f, 0.f, 0.f};
#pragma unroll
    for (int nt = 0; nt < 2; ++nt) {
        const float bb = bupd[(wq * 2 + nt) * 16 + ml];
#pragma unroll
        for (int i = 0; i < 4; ++i) {
            float v = acc[nt][i] + bb;
            v = v > 0.f ? v : 0.f;
            acc[nt][i] = v;
            sum[i] += v;
            ssq[i] += v * v;
        }
    }
#pragma unroll
    for (int m = 1; m < 16; m <<= 1) {
#pragma unroll
        for (int i = 0; i < 4; ++i) {
            sum[i] += __shfl_xor(sum[i], m);
            ssq[i] += __shfl_xor(ssq[i], m);
        }
    }
    if (ml == 0) {
#pragma unroll
        for (int i = 0; i < 4; ++i) {
            pS[kg * 4 + i][wq][0] = sum[i];
            pS[kg * 4 + i][wq][1] = ssq[i];
        }
    }
    __syncthreads();

    float mu[4], rs[4];
#pragma unroll
    for (int i = 0; i < 4; ++i) {
        int r = kg * 4 + i;
        float S = 0.f, Q = 0.f;
#pragma unroll
        for (int w = 0; w < 8; ++w) { S += pS[r][w][0]; Q += pS[r][w][1]; }
        float m = S * (1.f / 256.f);
        float var = Q * (1.f / 256.f) - m * m;
        mu[i] = m;
        rs[i] = rsqrtf(var + LN_EPS);
    }
#pragma unroll
    for (int nt = 0; nt < 2; ++nt) {
        const int cc = (wq * 2 + nt) * 16 + ml;
        const float g = gamma[cc], be = beta[cc];
#pragma unroll
        for (int i = 0; i < 4; ++i) {
            const int node = nb + kg * 4 + i;
            out[(size_t)node * DIM + cc] = (acc[nt][i] - mu[i]) * rs[i] * g + be;
        }
    }
}

extern "C" void kernel_launch(void* const* d_in, const int* in_sizes, int n_in,
                              void* d_out, int out_size, void* d_ws, size_t ws_size,
                              hipStream_t stream) {
    const float* x    = (const float*)d_in[0];
    const int*   eidx = (const int*)  d_in[1];
    const float* Wm   = (const float*)d_in[2];
    const float* bm   = (const float*)d_in[3];
    const float* Wu   = (const float*)d_in[4];
    const float* bu   = (const float*)d_in[5];
    const float* gam  = (const float*)d_in[6];
    const float* bet  = (const float*)d_in[7];
    float* out = (float*)d_out;

    char* ws = (char*)d_ws;
    ushort* xb     = (ushort*)(ws);                    //  5,120,000 B
    ushort* Ub     = (ushort*)(ws +  5120000);         //  5,120,000 B
    float*  Vf     = (float*) (ws + 10240000);         // 10,240,000 B
    ushort* Wcat   = (ushort*)(ws + 20480000);         //    262,144 B
    ushort* Wua    = (ushort*)(ws + 20742144);         //    262,144 B
    int*    cnt    = (int*)   (ws + 21004288);         //     40,960 B
    int*    srow   = (int*)   (ws + 21045248);         //  3,840,000 B (end ~24.9 MB)

    prep_all<<<3524, 256, 0, stream>>>(x, Wm, Wu, xb, Wcat, Wua, (int4*)cnt);
    scatter_uv<<<1875, 256, 0, stream>>>(eidx, cnt, srow, xb, Wcat, bm, Ub, Vf);
    edge_node<<<625, 512, 0, stream>>>(Ub, Vf, srow, cnt, xb, Wua, bu, gam, bet, out);
}